// Round 6
// baseline (252.069 us; speedup 1.0000x reference)
//
#include <hip/hip_runtime.h>
#include <hip/hip_bf16.h>

// x: [B=1024, N=65536] f32, index: [N] i32 permutation, group size 64.
#define BATCH   1024
#define NEUR    65536
#define NGRP    1024                  // groups (== BLK, thread t owns group t)
#define BLK     1024
#define NCHUNK  4
#define CHUNK   (NEUR / NCHUNK)       // 16384 floats staged per LDS chunk (64 KB)
#define CHUNK_F4 (CHUNK / 4)          // 4096 float4
#define F4_PER_THREAD (CHUNK_F4 / BLK) // 4
#define KMAX    24                    // padded slots per (chunk, group) cell
#define SENT    CHUNK                 // sentinel LDS slot, holds 0.0f
#define ROW_F4  (NEUR / 4)            // 16384
#define C_ITERS (ROW_F4 / BLK)        // 16
#define BUCKET_ELEMS (NCHUNK * KMAX * NGRP)   // 98304 u16
#define SPILL_CAP 1024

// ws: [group_of: 256 KB][bucket: 192 KB u16][spill: u32 count + entries]

__global__ void init_tables(unsigned short* __restrict__ bucket,
                            unsigned int* __restrict__ spill) {
    int i = blockIdx.x * blockDim.x + threadIdx.x;
    if (i < BUCKET_ELEMS) bucket[i] = (unsigned short)SENT;
    if (i == 0) spill[0] = 0;
}

// Wave == one group (64 consecutive permuted positions). Ballot/popcount gives
// each member a slot in its source-chunk cell; slots >= KMAX go to the spill
// list (expected ~30-40 entries total). Also builds the inverse-perm table.
__global__ void build_tables(const int* __restrict__ index,
                             int* __restrict__ group_of,
                             unsigned short* __restrict__ bucket,
                             unsigned int* __restrict__ spill) {
    const int p    = blockIdx.x * blockDim.x + threadIdx.x; // permuted position
    const int lane = threadIdx.x & 63;
    const int g    = p >> 6;                                // group id
    const int s    = index[p];                              // source neuron
    group_of[s] = g;
    const int c = s / CHUNK;                                // source chunk 0..3
    unsigned long long mc = 0;
    #pragma unroll
    for (int cc = 0; cc < NCHUNK; ++cc) {
        unsigned long long m = __ballot(c == cc);
        if (cc == c) mc = m;
    }
    const int k = __popcll(mc & ((1ull << lane) - 1ull));   // slot within cell
    if (k < KMAX) {
        bucket[((size_t)c * KMAX + k) * NGRP + g] = (unsigned short)(s & (CHUNK - 1));
    } else {
        unsigned int pos = atomicAdd(spill, 1u);
        if (pos < SPILL_CAP - 1)
            spill[1 + pos] = ((unsigned)g << 16) | (unsigned)s;
    }
}

// One block per batch row. Atomic-free (R3), gather-free in HBM (R4),
// branch-free fixed-trip k-loop (R5 lesson: ballot-break loop couldn't
// pipeline its L2->LDS dependent chain). Pad slots read a 0.0 sentinel.
__global__ __launch_bounds__(BLK, 8)
void lateral_norm_kernel(const float* __restrict__ x,
                         const int* __restrict__ group_of,
                         const unsigned short* __restrict__ bucket,
                         const unsigned int* __restrict__ spill,
                         float* __restrict__ out) {
    __shared__ float xs[CHUNK + 16];   // 64 KB chunk + sentinel at xs[SENT]
    __shared__ float rsum[NGRP];       // 4 KB

    const int b = blockIdx.x;
    const int t = threadIdx.x;
    const float4* __restrict__ xrow4 = (const float4*)(x + (size_t)b * NEUR);
    const float*  __restrict__ xrow  = x + (size_t)b * NEUR;

    if (t == 0) xs[SENT] = 0.0f;       // visible after first barrier

    float4 pre[F4_PER_THREAD];
    #pragma unroll
    for (int i = 0; i < F4_PER_THREAD; ++i) pre[i] = xrow4[i * BLK + t];

    float acc0 = 0.0f, acc1 = 0.0f;

    for (int c = 0; c < NCHUNK; ++c) {
        #pragma unroll
        for (int i = 0; i < F4_PER_THREAD; ++i) ((float4*)xs)[i * BLK + t] = pre[i];
        if (c + 1 < NCHUNK) {          // prefetch next chunk during k-loop
            #pragma unroll
            for (int i = 0; i < F4_PER_THREAD; ++i)
                pre[i] = xrow4[(c + 1) * CHUNK_F4 + i * BLK + t];
        }
        __syncthreads();
        // 24 independent, unconditional gather-adds; pads hit the 0.0 sentinel.
        const unsigned short* __restrict__ bk =
            bucket + (size_t)c * KMAX * NGRP + t;           // coalesced u16 rows
        #pragma unroll
        for (int k = 0; k < KMAX; k += 2) {
            acc0 += xs[bk[k * NGRP]];
            acc1 += xs[bk[(k + 1) * NGRP]];
        }
        __syncthreads();
    }

    // Rare overflow entries: broadcast scan (~30-40 iterations).
    const unsigned int ns = spill[0];
    for (unsigned int e = 0; e < ns; ++e) {
        const unsigned int ent = spill[1 + e];
        if ((int)(ent >> 16) == t) acc0 += xrow[ent & 0xFFFFu];  // L3-hot 4B read
    }

    rsum[t] = 1.0f / (acc0 + acc1);    // thread t owns group t
    __syncthreads();

    const int4* __restrict__ gof4  = (const int4*)group_of;
    float4*     __restrict__ orow4 = (float4*)(out + (size_t)b * NEUR);

    // Phase C: coalesced re-stream (L3-resident, R5-verified), scale, store.
    #pragma unroll
    for (int it = 0; it < C_ITERS; ++it) {
        const int e = it * BLK + t;
        const float4 v = xrow4[e];
        const int4  g = gof4[e];
        float4 o;
        o.x = v.x * rsum[g.x];
        o.y = v.y * rsum[g.y];
        o.z = v.z * rsum[g.z];
        o.w = v.w * rsum[g.w];
        orow4[e] = o;
    }
}

extern "C" void kernel_launch(void* const* d_in, const int* in_sizes, int n_in,
                              void* d_out, int out_size, void* d_ws, size_t ws_size,
                              hipStream_t stream) {
    const float* x     = (const float*)d_in[0];
    const int*   index = (const int*)d_in[1];
    float*       out   = (float*)d_out;

    int*            group_of = (int*)d_ws;                         // 256 KB
    unsigned short* bucket   = (unsigned short*)(group_of + NEUR); // 192 KB
    unsigned int*   spill    = (unsigned int*)(bucket + BUCKET_ELEMS);

    init_tables<<<(BUCKET_ELEMS + BLK - 1) / BLK, BLK, 0, stream>>>(bucket, spill);
    build_tables<<<NEUR / BLK, BLK, 0, stream>>>(index, group_of, bucket, spill);
    lateral_norm_kernel<<<BATCH, BLK, 0, stream>>>(x, group_of, bucket, spill, out);
}

// Round 7
// 186.619 us; speedup vs baseline: 1.3507x; 1.3507x over previous
//
#include <hip/hip_runtime.h>
#include <hip/hip_bf16.h>

// x: [B=1024, N=65536] f32, index: [N] i32 permutation, group size 64.
#define BATCH   1024
#define NEUR    65536
#define NGRP    1024                  // groups (thread t owns group t)
#define BLK     1024
#define NCHUNK  4
#define CHUNK   (NEUR / NCHUNK)       // 16384 floats per chunk (64 KB LDS)
#define CHUNK_F4 (CHUNK / 4)          // 4096 float4
#define F4T     (CHUNK_F4 / BLK)      // 4 float4 per thread
#define KMAX    24                    // padded slots per (chunk, group) cell
#define SENT    CHUNK                 // sentinel LDS slot holding 0.0f
#define ROW_F4  (NEUR / 4)            // 16384
#define C_ITERS (ROW_F4 / BLK)        // 16
#define BUCKET_ELEMS (NCHUNK * KMAX * NGRP)   // 98304 u16
#define SPILL_CAP 1024
#define NSUM    (BATCH * NGRP)        // 1 M floats = 4 MB

// ws: [group_of 256 KB][bucket 192 KB][spill 4 KB][sums 4 MB] ~= 4.5 MB

__global__ void init_tables(unsigned short* __restrict__ bucket,
                            unsigned int* __restrict__ spill,
                            float* __restrict__ sums) {
    int i = blockIdx.x * blockDim.x + threadIdx.x;
    if (i < BUCKET_ELEMS) bucket[i] = (unsigned short)SENT;
    if (i == 0) spill[0] = 0;
    if (i < NSUM) sums[i] = 0.0f;
}

// Wave == one group (64 consecutive permuted positions). Ballot/popcount gives
// each member a slot in its source-chunk cell; overflow (-0.6% of cells) goes
// to the spill list. Also builds the inverse-perm -> group table. (R6-proven.)
__global__ void build_tables(const int* __restrict__ index,
                             int* __restrict__ group_of,
                             unsigned short* __restrict__ bucket,
                             unsigned int* __restrict__ spill) {
    const int p    = blockIdx.x * blockDim.x + threadIdx.x; // permuted position
    const int lane = threadIdx.x & 63;
    const int g    = p >> 6;
    const int s    = index[p];                              // source neuron
    group_of[s] = g;
    const int c = s / CHUNK;
    unsigned long long mc = 0;
    #pragma unroll
    for (int cc = 0; cc < NCHUNK; ++cc) {
        unsigned long long m = __ballot(c == cc);
        if (cc == c) mc = m;
    }
    const int k = __popcll(mc & ((1ull << lane) - 1ull));
    if (k < KMAX) {
        bucket[((size_t)c * KMAX + k) * NGRP + g] = (unsigned short)(s & (CHUNK - 1));
    } else {
        unsigned int pos = atomicAdd(spill, 1u);
        if (pos < SPILL_CAP - 1)
            spill[1 + pos] = ((unsigned)g << 16) | (unsigned)s;
    }
}

// k1: one block per (row, chunk) — 4096 independent small blocks (16/CU).
// No cross-chunk serialization (R6 lesson: fat per-row blocks left every pipe
// idle). Stage 64 KB chunk, one barrier, 24 branch-free gather-adds, one
// global f32 atomic per thread into sums[b][g] (4-way contention).
__global__ __launch_bounds__(BLK, 8)
void k1_partial(const float* __restrict__ x,
                const unsigned short* __restrict__ bucket,
                float* __restrict__ sums) {
    __shared__ float xs[CHUNK + 16];
    const int bc = blockIdx.x;
    const int b  = bc >> 2;            // row
    const int c  = bc & 3;             // chunk
    const int t  = threadIdx.x;

    if (t == 0) xs[SENT] = 0.0f;

    const float4* __restrict__ src = (const float4*)(x + (size_t)b * NEUR + (size_t)c * CHUNK);
    #pragma unroll
    for (int i = 0; i < F4T; ++i) ((float4*)xs)[i * BLK + t] = src[i * BLK + t];
    __syncthreads();

    const unsigned short* __restrict__ bk = bucket + (size_t)c * KMAX * NGRP + t;
    float a0 = 0.0f, a1 = 0.0f;
    #pragma unroll
    for (int k = 0; k < KMAX; k += 2) {
        a0 += xs[bk[k * NGRP]];        // coalesced u16 list (L2-hot), random-bank LDS
        a1 += xs[bk[(k + 1) * NGRP]];  // pads hit the 0.0 sentinel
    }
    unsafeAtomicAdd(&sums[b * NGRP + t], a0 + a1);
}

// k3: one block per row, reverse order (L3-hottest rows first). Coalesced
// sums read + spill fixup + reciprocal, then the proven scale+store stream.
__global__ __launch_bounds__(BLK, 8)
void k3_scale(const float* __restrict__ x,
              const int* __restrict__ group_of,
              const float* __restrict__ sums,
              const unsigned int* __restrict__ spill,
              float* __restrict__ out) {
    __shared__ float rsum[NGRP];       // 4 KB only
    const int b = (BATCH - 1) - blockIdx.x;
    const int t = threadIdx.x;
    const float* __restrict__ xrow = x + (size_t)b * NEUR;

    float s = sums[b * NGRP + t];      // coalesced 4 KB
    const unsigned int ns = spill[0];  // ~40 entries: broadcast scan
    for (unsigned int e = 0; e < ns; ++e) {
        const unsigned int ent = spill[1 + e];
        if ((int)(ent >> 16) == t) s += xrow[ent & 0xFFFFu];
    }
    rsum[t] = 1.0f / s;
    __syncthreads();

    const float4* __restrict__ xrow4 = (const float4*)xrow;
    const int4*   __restrict__ gof4  = (const int4*)group_of;
    float4*       __restrict__ orow4 = (float4*)(out + (size_t)b * NEUR);

    #pragma unroll
    for (int it = 0; it < C_ITERS; ++it) {
        const int e = it * BLK + t;
        const float4 v = xrow4[e];     // L3-hot for late rows, HBM for early
        const int4  g = gof4[e];       // 256 KB table, L2-resident
        float4 o;
        o.x = v.x * rsum[g.x];
        o.y = v.y * rsum[g.y];
        o.z = v.z * rsum[g.z];
        o.w = v.w * rsum[g.w];
        orow4[e] = o;
    }
}

extern "C" void kernel_launch(void* const* d_in, const int* in_sizes, int n_in,
                              void* d_out, int out_size, void* d_ws, size_t ws_size,
                              hipStream_t stream) {
    const float* x     = (const float*)d_in[0];
    const int*   index = (const int*)d_in[1];
    float*       out   = (float*)d_out;

    int*            group_of = (int*)d_ws;                         // 256 KB
    unsigned short* bucket   = (unsigned short*)(group_of + NEUR); // 192 KB
    unsigned int*   spill    = (unsigned int*)(bucket + BUCKET_ELEMS); // 4 KB
    float*          sums     = (float*)(spill + SPILL_CAP);        // 4 MB

    init_tables<<<NSUM / BLK, BLK, 0, stream>>>(bucket, spill, sums);
    build_tables<<<NEUR / BLK, BLK, 0, stream>>>(index, group_of, bucket, spill);
    k1_partial<<<BATCH * NCHUNK, BLK, 0, stream>>>(x, bucket, sums);
    k3_scale<<<BATCH, BLK, 0, stream>>>(x, group_of, sums, spill, out);
}